// Round 4
// baseline (316.302 us; speedup 1.0000x reference)
//
#include <hip/hip_runtime.h>

// Problem constants from the reference
constexpr int B_ = 32;
constexpr int S_ = 2048;
constexpr int F_ = 512;
constexpr int ROWS = B_ * S_;          // 65536 rows of length F=512
constexpr int WAVES_PER_BLOCK = 4;     // 256 threads
constexpr int ROWS_PER_WAVE = 2;       // 8 rows/block -> 8192 blocks

// Native clang vector type — __builtin_nontemporal_store requires a real
// vector type, not HIP's HIP_vector_type struct.
typedef float f32x4 __attribute__((ext_vector_type(4)));

// out = one_hot(argmax_F(logits + gumbel)) per row.  (Reference's
// softmax/straight-through/top_k/scatter pipeline is the identity on the
// hard one-hot: non-argmax entries are exactly +0.0, and top_k(-mask, K)
// selects only already-zero entries since K < #zeros per sample.)
//
// R4 = R3 with the nontemporal-store type fixed:
//  - Output stores are NON-TEMPORAL: out (134 MB) must not allocate in
//    L2/L3, so the 268 MB of inputs (L3-resident after the harness restore)
//    stay cached. R2 showed FETCH_SIZE == 50% of reads == output-sized
//    L3 evictions.
//  - Each output line is written exactly once (1.0 inlined into the vector
//    store).
//  - 2 rows/wave: modest MLP that fits the register budget.
__global__ __launch_bounds__(256) void gumbel_hard_onehot_kernel(
    const float* __restrict__ logits,
    const float* __restrict__ gumbel,
    float* __restrict__ out)
{
    const int lane = threadIdx.x & 63;
    const int wave = threadIdx.x >> 6;
    const int rowbase = (blockIdx.x * WAVES_PER_BLOCK + wave) * ROWS_PER_WAVE;

    const size_t base_off = (size_t)rowbase * F_;
    const f32x4* __restrict__ lg = (const f32x4*)(logits + base_off);
    const f32x4* __restrict__ gm = (const f32x4*)(gumbel + base_off);
    f32x4* __restrict__ op = (f32x4*)(out + base_off);

    // Issue both rows' loads up front (8x float4 = 32 VGPR of payload).
    f32x4 A0[ROWS_PER_WAVE], A1[ROWS_PER_WAVE], G0[ROWS_PER_WAVE], G1[ROWS_PER_WAVE];
#pragma unroll
    for (int r = 0; r < ROWS_PER_WAVE; ++r) {
        A0[r] = lg[r * 128 + lane];
        A1[r] = lg[r * 128 + lane + 64];
        G0[r] = gm[r * 128 + lane];
        G1[r] = gm[r * 128 + lane + 64];
    }

#pragma unroll
    for (int r = 0; r < ROWS_PER_WAVE; ++r) {
        float v[8];
        v[0] = A0[r].x + G0[r].x; v[1] = A0[r].y + G0[r].y;
        v[2] = A0[r].z + G0[r].z; v[3] = A0[r].w + G0[r].w;
        v[4] = A1[r].x + G1[r].x; v[5] = A1[r].y + G1[r].y;
        v[6] = A1[r].z + G1[r].z; v[7] = A1[r].w + G1[r].w;

        // Local max of 8 (tree), then 6-step wave-wide max butterfly.
        float m01 = fmaxf(v[0], v[1]), m23 = fmaxf(v[2], v[3]);
        float m45 = fmaxf(v[4], v[5]), m67 = fmaxf(v[6], v[7]);
        float best = fmaxf(fmaxf(m01, m23), fmaxf(m45, m67));
#pragma unroll
        for (int off = 32; off > 0; off >>= 1)
            best = fmaxf(best, __shfl_xor(best, off, 64));
        // max is a selection -> 'best' is exactly some v element; == finds it.

        // First-index argmax. Lane L holds global indices 4L..4L+3 (half0)
        // and 256+4L..4L+3 (half1); lane-major order preserves index order
        // within each half, and all of half0 precedes half1.
        int j0 = 4, j1 = 4;
#pragma unroll
        for (int j = 3; j >= 0; --j) {
            if (v[j] == best)     j0 = j;
            if (v[4 + j] == best) j1 = j;
        }
        unsigned long long bal0 = __ballot(j0 < 4);
        unsigned long long bal1 = __ballot(j1 < 4);
        int cand0 = 4 * lane + j0;
        int cand1 = 256 + 4 * lane + j1;

        int idx;
        if (bal0) {
            idx = __shfl(cand0, __builtin_ctzll(bal0), 64);
        } else {
            idx = __shfl(cand1, __builtin_ctzll(bal1), 64);
        }

        // Build one-hot output, each line written exactly once, non-temporal.
        const int e0 = 4 * lane;        // element index of z0.x
        const int e1 = 256 + 4 * lane;  // element index of z1.x
        f32x4 z0, z1;
        z0.x = (e0 + 0 == idx) ? 1.0f : 0.0f;
        z0.y = (e0 + 1 == idx) ? 1.0f : 0.0f;
        z0.z = (e0 + 2 == idx) ? 1.0f : 0.0f;
        z0.w = (e0 + 3 == idx) ? 1.0f : 0.0f;
        z1.x = (e1 + 0 == idx) ? 1.0f : 0.0f;
        z1.y = (e1 + 1 == idx) ? 1.0f : 0.0f;
        z1.z = (e1 + 2 == idx) ? 1.0f : 0.0f;
        z1.w = (e1 + 3 == idx) ? 1.0f : 0.0f;

        __builtin_nontemporal_store(z0, &op[r * 128 + lane]);
        __builtin_nontemporal_store(z1, &op[r * 128 + lane + 64]);
    }
}

extern "C" void kernel_launch(void* const* d_in, const int* in_sizes, int n_in,
                              void* d_out, int out_size, void* d_ws, size_t ws_size,
                              hipStream_t stream) {
    const float* logits = (const float*)d_in[0];
    const float* gumbel = (const float*)d_in[1];
    float* out = (float*)d_out;

    const int grid = ROWS / (WAVES_PER_BLOCK * ROWS_PER_WAVE);  // 8192 blocks
    gumbel_hard_onehot_kernel<<<grid, 256, 0, stream>>>(logits, gumbel, out);
}

// Round 5
// 287.530 us; speedup vs baseline: 1.1001x; 1.1001x over previous
//
#include <hip/hip_runtime.h>

// Problem constants from the reference
constexpr int B_ = 32;
constexpr int S_ = 2048;
constexpr int F_ = 512;
constexpr int ROWS = B_ * S_;          // 65536 rows of length F=512
constexpr int WAVES_PER_BLOCK = 4;     // 256 threads

typedef float f32x4 __attribute__((ext_vector_type(4)));

// out = one_hot(argmax_F(logits + gumbel)) per row.  (Reference's
// softmax/straight-through/top_k/scatter pipeline is the identity on the
// hard one-hot: non-argmax entries are exactly +0.0, and top_k(-mask, K)
// selects only already-zero entries since K < #zeros per sample.)
//
// R5: split into a READ-ONLY phase and a WRITE-ONLY phase.
//  k1: per-row argmax (268 MB streaming read, 256 KB index write to d_ws).
//      NT loads: inputs are read-once; don't let L3 fills evict unread
//      input lines (268 MB inputs vs 256 MB L3 — only ~half resident).
//  k2: one-hot expansion (134 MB streaming write, index reads are L2 hits).
// Rationale: R1-R4 all sit at 113-126 us regardless of in-kernel structure;
// mixed 2:1 read:write with reduce-gated stores runs at 3.56 TB/s effective
// vs the 6.3 TB/s copy ceiling. Unidirectional phases should each run near
// their own roofline.

__global__ __launch_bounds__(256) void argmax_phase_kernel(
    const float* __restrict__ logits,
    const float* __restrict__ gumbel,
    int* __restrict__ row_idx)
{
    const int lane = threadIdx.x & 63;
    const int wave = threadIdx.x >> 6;
    const int row  = blockIdx.x * WAVES_PER_BLOCK + wave;  // 1 row per wave

    const size_t row_off = (size_t)row * F_;
    const f32x4* __restrict__ lg = (const f32x4*)(logits + row_off);
    const f32x4* __restrict__ gm = (const f32x4*)(gumbel + row_off);

    // 512 floats / row = 128 f32x4. Lane i handles slots i and i+64.
    f32x4 a0 = __builtin_nontemporal_load(&lg[lane]);
    f32x4 a1 = __builtin_nontemporal_load(&lg[lane + 64]);
    f32x4 b0 = __builtin_nontemporal_load(&gm[lane]);
    f32x4 b1 = __builtin_nontemporal_load(&gm[lane + 64]);

    float v[8];
    v[0] = a0.x + b0.x; v[1] = a0.y + b0.y; v[2] = a0.z + b0.z; v[3] = a0.w + b0.w;
    v[4] = a1.x + b1.x; v[5] = a1.y + b1.y; v[6] = a1.z + b1.z; v[7] = a1.w + b1.w;

    // Local max of 8 (tree), then 6-step wave-wide max butterfly (value only).
    float m01 = fmaxf(v[0], v[1]), m23 = fmaxf(v[2], v[3]);
    float m45 = fmaxf(v[4], v[5]), m67 = fmaxf(v[6], v[7]);
    float best = fmaxf(fmaxf(m01, m23), fmaxf(m45, m67));
#pragma unroll
    for (int off = 32; off > 0; off >>= 1)
        best = fmaxf(best, __shfl_xor(best, off, 64));
    // max is a selection -> best is exactly some v element; == finds it.

    // First-index argmax. Lane L holds global indices 4L..4L+3 (half0) and
    // 256+4L..4L+3 (half1); all of half0 precedes half1.
    int j0 = 4, j1 = 4;
#pragma unroll
    for (int j = 3; j >= 0; --j) {
        if (v[j] == best)     j0 = j;
        if (v[4 + j] == best) j1 = j;
    }
    unsigned long long bal0 = __ballot(j0 < 4);
    unsigned long long bal1 = __ballot(j1 < 4);
    int cand0 = 4 * lane + j0;
    int cand1 = 256 + 4 * lane + j1;

    int idx;
    if (bal0) {
        idx = __shfl(cand0, __builtin_ctzll(bal0), 64);
    } else {
        idx = __shfl(cand1, __builtin_ctzll(bal1), 64);
    }

    if (lane == 0) row_idx[row] = idx;
}

// Pure streaming write: each thread emits two f32x4 (32 B), grid-stride by
// half the slot count so both passes are fully coalesced.
constexpr int F4_PER_ROW   = F_ / 4;                 // 128
constexpr size_t TOTAL_F4  = (size_t)ROWS * F4_PER_ROW;   // 8388608
constexpr int K2_BLOCKS    = (int)(TOTAL_F4 / 2 / 256);   // 16384

__global__ __launch_bounds__(256) void onehot_phase_kernel(
    const int* __restrict__ row_idx,
    float* __restrict__ out)
{
    const size_t tid = (size_t)blockIdx.x * 256 + threadIdx.x;
    f32x4* __restrict__ op = (f32x4*)out;

#pragma unroll
    for (int p = 0; p < 2; ++p) {
        const size_t slot = tid + (size_t)p * (TOTAL_F4 / 2);
        const int row  = (int)(slot >> 7);           // 128 f4 per row
        const int ebase = ((int)slot & 127) * 4;     // element index of .x
        const int idx = row_idx[row];                // L2-hit broadcast

        f32x4 z;
        z.x = (ebase + 0 == idx) ? 1.0f : 0.0f;
        z.y = (ebase + 1 == idx) ? 1.0f : 0.0f;
        z.z = (ebase + 2 == idx) ? 1.0f : 0.0f;
        z.w = (ebase + 3 == idx) ? 1.0f : 0.0f;
        op[slot] = z;
    }
}

extern "C" void kernel_launch(void* const* d_in, const int* in_sizes, int n_in,
                              void* d_out, int out_size, void* d_ws, size_t ws_size,
                              hipStream_t stream) {
    const float* logits = (const float*)d_in[0];
    const float* gumbel = (const float*)d_in[1];
    float* out = (float*)d_out;
    int* row_idx = (int*)d_ws;   // 65536 * 4 B = 256 KB of workspace

    const int grid1 = ROWS / WAVES_PER_BLOCK;  // 16384 blocks
    argmax_phase_kernel<<<grid1, 256, 0, stream>>>(logits, gumbel, row_idx);
    onehot_phase_kernel<<<K2_BLOCKS, 256, 0, stream>>>(row_idx, out);
}